// Round 1
// baseline (613.196 us; speedup 1.0000x reference)
//
#include <hip/hip_runtime.h>
#include <hip/hip_bf16.h>

#define D_MODEL 1024
#define RANK 64
#define NCOMP 16
#define NKNOW 16384
#define TOPK 8
#define NTOK 8192   // B*S

typedef __attribute__((ext_vector_type(4))) float f32x4;
typedef __attribute__((ext_vector_type(8))) short s16x8;

static __device__ __forceinline__ unsigned short f2bf(float f) {
  union { float f; unsigned u; } v; v.f = f;
  unsigned r = v.u + 0x7FFFu + ((v.u >> 16) & 1u);
  return (unsigned short)(r >> 16);
}

// ---------------------------------------------------------------------------
// K1: T = X (8192x1024) @ B (1024x1024), where B[d][c] = cn[c>>6][d][c&63]
// 128x128 tile, 256 threads, 8x8 micro-tile, DK=16.
// ---------------------------------------------------------------------------
__global__ __launch_bounds__(256) void k1_gemm(const float* __restrict__ X,
                                               const float* __restrict__ CN,
                                               float* __restrict__ T) {
  __shared__ float As[16][132];
  __shared__ float Bs[16][132];
  const int bx = blockIdx.x & 7;        // col block 0..7
  const int by = blockIdx.x >> 3;       // row block 0..63
  const int tid = threadIdx.x;
  const int tx = tid & 15, ty = tid >> 4;
  const int row0 = by * 128, col0 = bx * 128;

  // A staging: thread loads 8 floats at row ar, k-cols ac..ac+7
  const int ar = tid >> 1;              // 0..127
  const int ac = (tid & 1) * 8;         // 0 or 8
  const float* Aptr = X + (size_t)(row0 + ar) * 1024 + ac;
  // B staging: d-row bd, cols bc..bc+7 (8-run never straddles an n boundary)
  const int bd = tid >> 4;              // 0..15
  const int bc = (tid & 15) * 8;        // 0..120
  const float* Bptr = CN + (size_t)((col0 + bc) >> 6) * (1024 * 64) + bd * 64
                         + ((col0 + bc) & 63);

  float acc[8][8];
#pragma unroll
  for (int i = 0; i < 8; i++)
#pragma unroll
    for (int j = 0; j < 8; j++) acc[i][j] = 0.f;

  f32x4 a0 = *(const f32x4*)(Aptr);
  f32x4 a1 = *(const f32x4*)(Aptr + 4);
  f32x4 b0 = *(const f32x4*)(Bptr);
  f32x4 b1 = *(const f32x4*)(Bptr + 4);

  for (int k0 = 0; k0 < 1024; k0 += 16) {
    __syncthreads();
#pragma unroll
    for (int j = 0; j < 4; j++) {
      As[ac + j][ar] = a0[j];
      As[ac + 4 + j][ar] = a1[j];
    }
    *(f32x4*)&Bs[bd][bc] = b0;
    *(f32x4*)&Bs[bd][bc + 4] = b1;
    __syncthreads();
    if (k0 + 16 < 1024) {
      a0 = *(const f32x4*)(Aptr + k0 + 16);
      a1 = *(const f32x4*)(Aptr + k0 + 16 + 4);
      b0 = *(const f32x4*)(Bptr + (size_t)(k0 + 16) * 64);
      b1 = *(const f32x4*)(Bptr + (size_t)(k0 + 16) * 64 + 4);
    }
#pragma unroll
    for (int d = 0; d < 16; d++) {
      f32x4 av0 = *(const f32x4*)&As[d][ty * 8];
      f32x4 av1 = *(const f32x4*)&As[d][ty * 8 + 4];
      f32x4 bv0 = *(const f32x4*)&Bs[d][tx * 8];
      f32x4 bv1 = *(const f32x4*)&Bs[d][tx * 8 + 4];
#pragma unroll
      for (int i = 0; i < 4; i++) {
#pragma unroll
        for (int j = 0; j < 4; j++) {
          acc[i][j]         = fmaf(av0[i], bv0[j], acc[i][j]);
          acc[i][j + 4]     = fmaf(av0[i], bv1[j], acc[i][j + 4]);
          acc[i + 4][j]     = fmaf(av1[i], bv0[j], acc[i + 4][j]);
          acc[i + 4][j + 4] = fmaf(av1[i], bv1[j], acc[i + 4][j + 4]);
        }
      }
    }
  }
#pragma unroll
  for (int i = 0; i < 8; i++) {
    float* op = T + (size_t)(row0 + ty * 8 + i) * 1024 + col0 + tx * 8;
    *(f32x4*)op = *(f32x4*)&acc[i][0];
    *(f32x4*)(op + 4) = *(f32x4*)&acc[i][4];
  }
}

// ---------------------------------------------------------------------------
// K1b: Q[tok][r] = sum_n mw[tok][n] * T[tok][n*64+r]; also emit bf16 copy.
// ---------------------------------------------------------------------------
__global__ __launch_bounds__(256) void k1b_weight(const float* __restrict__ T,
                                                  const float* __restrict__ MW,
                                                  float* __restrict__ Qf,
                                                  unsigned short* __restrict__ Qb) {
  const int gid = blockIdx.x * 256 + threadIdx.x;  // 0..524287
  const int tok = gid >> 6, r = gid & 63;
  float q = 0.f;
#pragma unroll
  for (int n = 0; n < 16; n++)
    q = fmaf(MW[tok * 16 + n], T[(size_t)tok * 1024 + n * 64 + r], q);
  Qf[gid] = q;
  Qb[gid] = f2bf(q);
}

// ---------------------------------------------------------------------------
// K1c: Kb = bf16(knowledge_K)
// ---------------------------------------------------------------------------
__global__ __launch_bounds__(256) void k1c_cvt(const float* __restrict__ Kf,
                                               unsigned short* __restrict__ Kb) {
  const int gid = blockIdx.x * 256 + threadIdx.x;  // one per 4 elems
  f32x4 v = *(const f32x4*)(Kf + (size_t)gid * 4);
  unsigned short o0 = f2bf(v[0]), o1 = f2bf(v[1]), o2 = f2bf(v[2]), o3 = f2bf(v[3]);
  unsigned long long pack = (unsigned long long)o0 | ((unsigned long long)o1 << 16)
                          | ((unsigned long long)o2 << 32) | ((unsigned long long)o3 << 48);
  *(unsigned long long*)(Kb + (size_t)gid * 4) = pack;
}

// ---------------------------------------------------------------------------
// K2: bf16-MFMA screening -> per-lane top-8 candidates -> exact f32 rescore
//     -> exact top-8 (jax tie-break) -> softmax -> gather V -> output.
// One block = 16 tokens, 4 waves; wave w screens j in [w*4096,(w+1)*4096).
// ---------------------------------------------------------------------------
__global__ __launch_bounds__(256) void k2_select(
    const float* __restrict__ Qf, const unsigned short* __restrict__ Qb,
    const float* __restrict__ Kf, const unsigned short* __restrict__ Kb,
    const float* __restrict__ V,
    float* __restrict__ out,       // [8192][1024]
    float* __restrict__ out_idx,   // [8192][8] (as float)
    float* __restrict__ out_w) {   // [8192][8]
  __shared__ float qs[16][64];
  __shared__ int cand[16][128];
  __shared__ int tki[16][8];
  __shared__ float tkw[16][8];

  const int tid = threadIdx.x;
  const int wv = tid >> 6;        // wave 0..3
  const int lane = tid & 63;
  const int tb = blockIdx.x * 16;

  // stage Qf rows for this block's 16 tokens
  {
    const int idx = tid * 4;
    const int t = idx >> 6, k = idx & 63;
    *(f32x4*)&qs[t][k] = *(const f32x4*)(Qf + (size_t)(tb + t) * 64 + k);
  }

  // B-fragments: col = token = lane&15, k-slice = (lane>>4)*8
  const int myTok = lane & 15;
  const int slice = lane >> 4;    // 0..3
  const s16x8 bf0 = *(const s16x8*)(Qb + (size_t)(tb + myTok) * 64 + slice * 8);
  const s16x8 bf1 = *(const s16x8*)(Qb + (size_t)(tb + myTok) * 64 + 32 + slice * 8);

  float ls[8];
  int li[8];
#pragma unroll
  for (int q = 0; q < 8; q++) { ls[q] = -1e30f; li[q] = 0; }

  const int jwave = wv * 4096;
  for (int tt = 0; tt < 256; ++tt) {
    const int jbase = jwave + tt * 16;
    const unsigned short* ap = Kb + (size_t)(jbase + (lane & 15)) * 64 + slice * 8;
    s16x8 af0 = *(const s16x8*)(ap);
    s16x8 af1 = *(const s16x8*)(ap + 32);
    f32x4 c = {0.f, 0.f, 0.f, 0.f};
    c = __builtin_amdgcn_mfma_f32_16x16x32_bf16(af0, bf0, c, 0, 0, 0);
    c = __builtin_amdgcn_mfma_f32_16x16x32_bf16(af1, bf1, c, 0, 0, 0);
#pragma unroll
    for (int r = 0; r < 4; r++) {
      const float sc = c[r];                 // unscaled score (monotonic)
      const int j = jbase + slice * 4 + r;   // C row = (lane>>4)*4 + r
      if (sc > ls[7]) {
        ls[7] = sc; li[7] = j;
#pragma unroll
        for (int q = 7; q > 0; q--) {
          if (ls[q] > ls[q - 1]) {
            float tf = ls[q]; ls[q] = ls[q - 1]; ls[q - 1] = tf;
            int ti = li[q]; li[q] = li[q - 1]; li[q - 1] = ti;
          }
        }
      }
    }
  }
  // dump candidates: 128 distinct j's per token
#pragma unroll
  for (int q = 0; q < 8; q++) cand[myTok][wv * 32 + slice * 8 + q] = li[q];
  __syncthreads();

  // exact rescore + selection: wave wv handles tokens wv*4 .. wv*4+3
  for (int u = 0; u < 4; ++u) {
    const int t = wv * 4 + u;
    const int ja = cand[t][lane];
    const int jb = cand[t][lane + 64];
    float sa = 0.f, sb = 0.f;
#pragma unroll
    for (int k = 0; k < 64; k += 4) {
      f32x4 qv = *(const f32x4*)&qs[t][k];
      f32x4 ka = *(const f32x4*)(Kf + (size_t)ja * 64 + k);
      f32x4 kb = *(const f32x4*)(Kf + (size_t)jb * 64 + k);
#pragma unroll
      for (int e = 0; e < 4; e++) {
        sa = fmaf(qv[e], ka[e], sa);
        sb = fmaf(qv[e], kb[e], sb);
      }
    }
    sa *= 0.125f; sb *= 0.125f;

    bool taka = false, takb = false;
    float wsv[8]; int wjv[8];
#pragma unroll
    for (int r = 0; r < 8; r++) {
      float ms = taka ? -1e30f : sa; int mj = taka ? 0x7fffffff : ja;
      float os = takb ? -1e30f : sb; int oj = takb ? 0x7fffffff : jb;
      if (os > ms || (os == ms && oj < mj)) { ms = os; mj = oj; }
#pragma unroll
      for (int d = 1; d < 64; d <<= 1) {
        float rs = __shfl_xor(ms, d);
        int rj = __shfl_xor(mj, d);
        if (rs > ms || (rs == ms && rj < mj)) { ms = rs; mj = rj; }
      }
      wsv[r] = ms; wjv[r] = mj;
      if (mj == ja) taka = true;
      if (mj == jb) takb = true;
    }

    // softmax over the sorted top-8 (computed redundantly on all lanes)
    const float m = wsv[0];
    float ex[8], sum = 0.f;
#pragma unroll
    for (int r = 0; r < 8; r++) { ex[r] = expf(wsv[r] - m); sum += ex[r]; }
    if (lane < 8) {
      const int r = lane;
      const int gt = tb + t;
      const float w = ex[r] / sum;
      out_idx[(size_t)gt * 8 + r] = (float)wjv[r];
      out_w[(size_t)gt * 8 + r] = w;
      tki[t][r] = wjv[r];
      tkw[t][r] = w;
    }
  }
  __syncthreads();

  // gather V and produce output. thread -> (token = tid>>4, 16B slot = tid&15)
  {
    const int t = tid >> 4;
    const int l16 = tid & 15;
    f32x4 acc[16];
#pragma unroll
    for (int cIdx = 0; cIdx < 16; cIdx++) acc[cIdx] = (f32x4){0.f, 0.f, 0.f, 0.f};
#pragma unroll
    for (int k = 0; k < 8; k++) {
      const float w = tkw[t][k];
      const float* vp = V + (size_t)tki[t][k] * 1024 + l16 * 4;
#pragma unroll
      for (int cIdx = 0; cIdx < 16; cIdx++) {
        f32x4 vv = *(const f32x4*)(vp + cIdx * 64);
        acc[cIdx] += w * vv;
      }
    }
    float* op = out + (size_t)(tb + t) * 1024 + l16 * 4;
#pragma unroll
    for (int cIdx = 0; cIdx < 16; cIdx++) *(f32x4*)(op + cIdx * 64) = acc[cIdx];
  }
}

// ---------------------------------------------------------------------------
extern "C" void kernel_launch(void* const* d_in, const int* in_sizes, int n_in,
                              void* d_out, int out_size, void* d_ws, size_t ws_size,
                              hipStream_t stream) {
  const float* x  = (const float*)d_in[0];   // [2,4096,1024]
  const float* mw = (const float*)d_in[1];   // [2,4096,16]
  const float* cn = (const float*)d_in[2];   // [16,1024,64]
  const float* kK = (const float*)d_in[3];   // [16384,64]
  const float* kV = (const float*)d_in[4];   // [16384,1024]

  float* out  = (float*)d_out;               // 8192*1024
  float* oidx = out + (size_t)NTOK * D_MODEL;       // 8192*8
  float* ow   = oidx + (size_t)NTOK * TOPK;         // 8192*8

  // workspace layout
  float* T = (float*)d_ws;                                        // 33554432 B
  float* Qf = (float*)((char*)d_ws + 33554432);                   // 2097152 B
  unsigned short* Qb = (unsigned short*)((char*)d_ws + 35651584); // 1048576 B
  unsigned short* Kb = (unsigned short*)((char*)d_ws + 36700160); // 2097152 B

  k1_gemm<<<512, 256, 0, stream>>>(x, cn, T);
  k1b_weight<<<2048, 256, 0, stream>>>(T, mw, Qf, Qb);
  k1c_cvt<<<1024, 256, 0, stream>>>(kK, Kb);
  k2_select<<<512, 256, 0, stream>>>(Qf, Qb, kK, Kb, kV, out, oidx, ow);

  (void)in_sizes; (void)n_in; (void)out_size; (void)ws_size;
}

// Round 2
// 486.077 us; speedup vs baseline: 1.2615x; 1.2615x over previous
//
#include <hip/hip_runtime.h>
#include <hip/hip_bf16.h>

#define D_MODEL 1024
#define RANK 64
#define NCOMP 16
#define NKNOW 16384
#define TOPK 8
#define NTOK 8192   // B*S

typedef __attribute__((ext_vector_type(4))) float f32x4;
typedef __attribute__((ext_vector_type(8))) short s16x8;

static __device__ __forceinline__ unsigned short f2bf(float f) {
  union { float f; unsigned u; } v; v.f = f;
  unsigned r = v.u + 0x7FFFu + ((v.u >> 16) & 1u);
  return (unsigned short)(r >> 16);
}

// ---------------------------------------------------------------------------
// K1: T = X (8192x1024) @ B (1024x1024), where B[d][c] = cn[c>>6][d][c&63]
// 128x128 tile, 256 threads, 8x8 micro-tile, DK=16.
// ---------------------------------------------------------------------------
__global__ __launch_bounds__(256) void k1_gemm(const float* __restrict__ X,
                                               const float* __restrict__ CN,
                                               float* __restrict__ T) {
  __shared__ float As[16][132];
  __shared__ float Bs[16][132];
  const int bx = blockIdx.x & 7;        // col block 0..7
  const int by = blockIdx.x >> 3;       // row block 0..63
  const int tid = threadIdx.x;
  const int tx = tid & 15, ty = tid >> 4;
  const int row0 = by * 128, col0 = bx * 128;

  const int ar = tid >> 1;              // 0..127
  const int ac = (tid & 1) * 8;         // 0 or 8
  const float* Aptr = X + (size_t)(row0 + ar) * 1024 + ac;
  const int bd = tid >> 4;              // 0..15
  const int bc = (tid & 15) * 8;        // 0..120
  const float* Bptr = CN + (size_t)((col0 + bc) >> 6) * (1024 * 64) + bd * 64
                         + ((col0 + bc) & 63);

  float acc[8][8];
#pragma unroll
  for (int i = 0; i < 8; i++)
#pragma unroll
    for (int j = 0; j < 8; j++) acc[i][j] = 0.f;

  f32x4 a0 = *(const f32x4*)(Aptr);
  f32x4 a1 = *(const f32x4*)(Aptr + 4);
  f32x4 b0 = *(const f32x4*)(Bptr);
  f32x4 b1 = *(const f32x4*)(Bptr + 4);

  for (int k0 = 0; k0 < 1024; k0 += 16) {
    __syncthreads();
#pragma unroll
    for (int j = 0; j < 4; j++) {
      As[ac + j][ar] = a0[j];
      As[ac + 4 + j][ar] = a1[j];
    }
    *(f32x4*)&Bs[bd][bc] = b0;
    *(f32x4*)&Bs[bd][bc + 4] = b1;
    __syncthreads();
    if (k0 + 16 < 1024) {
      a0 = *(const f32x4*)(Aptr + k0 + 16);
      a1 = *(const f32x4*)(Aptr + k0 + 16 + 4);
      b0 = *(const f32x4*)(Bptr + (size_t)(k0 + 16) * 64);
      b1 = *(const f32x4*)(Bptr + (size_t)(k0 + 16) * 64 + 4);
    }
#pragma unroll
    for (int d = 0; d < 16; d++) {
      f32x4 av0 = *(const f32x4*)&As[d][ty * 8];
      f32x4 av1 = *(const f32x4*)&As[d][ty * 8 + 4];
      f32x4 bv0 = *(const f32x4*)&Bs[d][tx * 8];
      f32x4 bv1 = *(const f32x4*)&Bs[d][tx * 8 + 4];
#pragma unroll
      for (int i = 0; i < 4; i++) {
#pragma unroll
        for (int j = 0; j < 4; j++) {
          acc[i][j]         = fmaf(av0[i], bv0[j], acc[i][j]);
          acc[i][j + 4]     = fmaf(av0[i], bv1[j], acc[i][j + 4]);
          acc[i + 4][j]     = fmaf(av1[i], bv0[j], acc[i + 4][j]);
          acc[i + 4][j + 4] = fmaf(av1[i], bv1[j], acc[i + 4][j + 4]);
        }
      }
    }
  }
#pragma unroll
  for (int i = 0; i < 8; i++) {
    float* op = T + (size_t)(row0 + ty * 8 + i) * 1024 + col0 + tx * 8;
    *(f32x4*)op = *(f32x4*)&acc[i][0];
    *(f32x4*)(op + 4) = *(f32x4*)&acc[i][4];
  }
}

// ---------------------------------------------------------------------------
// K1b: Q[tok][r] = sum_n mw[tok][n] * T[tok][n*64+r]; also emit bf16 copy.
// ---------------------------------------------------------------------------
__global__ __launch_bounds__(256) void k1b_weight(const float* __restrict__ T,
                                                  const float* __restrict__ MW,
                                                  float* __restrict__ Qf,
                                                  unsigned short* __restrict__ Qb) {
  const int gid = blockIdx.x * 256 + threadIdx.x;  // 0..524287
  const int tok = gid >> 6, r = gid & 63;
  float q = 0.f;
#pragma unroll
  for (int n = 0; n < 16; n++)
    q = fmaf(MW[tok * 16 + n], T[(size_t)tok * 1024 + n * 64 + r], q);
  Qf[gid] = q;
  Qb[gid] = f2bf(q);
}

// ---------------------------------------------------------------------------
// K1c: Kb = bf16(knowledge_K)
// ---------------------------------------------------------------------------
__global__ __launch_bounds__(256) void k1c_cvt(const float* __restrict__ Kf,
                                               unsigned short* __restrict__ Kb) {
  const int gid = blockIdx.x * 256 + threadIdx.x;  // one per 4 elems
  f32x4 v = *(const f32x4*)(Kf + (size_t)gid * 4);
  unsigned short o0 = f2bf(v[0]), o1 = f2bf(v[1]), o2 = f2bf(v[2]), o3 = f2bf(v[3]);
  unsigned long long pack = (unsigned long long)o0 | ((unsigned long long)o1 << 16)
                          | ((unsigned long long)o2 << 32) | ((unsigned long long)o3 << 48);
  *(unsigned long long*)(Kb + (size_t)gid * 4) = pack;
}

// ---------------------------------------------------------------------------
// K2a: bf16-MFMA screening. 8192 independent waves. Wave = (token-group tg,
// j-slice jsl): screens j in [jsl*1024, +1024) for tokens tg*16..+16.
// Per-lane unsorted top-8 (min-threshold tracking). Writes 512 candidates
// (j + raw bf16 score) per token.
// ---------------------------------------------------------------------------
__global__ __launch_bounds__(256) void k2a_screen(
    const unsigned short* __restrict__ Qb,
    const unsigned short* __restrict__ Kb,
    int* __restrict__ cand_idx, float* __restrict__ cand_score) {
  const int tid = threadIdx.x;
  const int wv = tid >> 6, lane = tid & 63;
  const int gw = blockIdx.x * 4 + wv;     // 0..8191
  const int tg = gw >> 4;                 // token group 0..511
  const int jsl = gw & 15;                // j-slice 0..15
  const int tb = tg * 16;
  const int myTok = lane & 15;
  const int slice = lane >> 4;            // 0..3

  const s16x8 bf0 = *(const s16x8*)(Qb + (size_t)(tb + myTok) * 64 + slice * 8);
  const s16x8 bf1 = *(const s16x8*)(Qb + (size_t)(tb + myTok) * 64 + 32 + slice * 8);

  float ls[8]; int li[8];
#pragma unroll
  for (int q = 0; q < 8; q++) { ls[q] = -1e30f; li[q] = 0; }
  float thr = -1e30f;

  const int j0 = jsl * 1024;
  const unsigned short* ap0 = Kb + (size_t)(j0 + myTok) * 64 + slice * 8;
  s16x8 af0 = *(const s16x8*)(ap0);
  s16x8 af1 = *(const s16x8*)(ap0 + 32);
  for (int tt = 0; tt < 64; ++tt) {
    f32x4 c = {0.f, 0.f, 0.f, 0.f};
    c = __builtin_amdgcn_mfma_f32_16x16x32_bf16(af0, bf0, c, 0, 0, 0);
    c = __builtin_amdgcn_mfma_f32_16x16x32_bf16(af1, bf1, c, 0, 0, 0);
    if (tt + 1 < 64) {
      const unsigned short* ap = ap0 + (size_t)(tt + 1) * 16 * 64;
      af0 = *(const s16x8*)(ap);
      af1 = *(const s16x8*)(ap + 32);
    }
    const int jb = j0 + tt * 16 + slice * 4;
#pragma unroll
    for (int r = 0; r < 4; r++) {
      const float sc = c[r];
      if (sc > thr) {
        const int j = jb + r;
        bool done = false;
#pragma unroll
        for (int q = 0; q < 8; q++) {
          const bool hit = (!done) && (ls[q] == thr);
          if (hit) { ls[q] = sc; li[q] = j; done = true; }
        }
        thr = fminf(fminf(fminf(ls[0], ls[1]), fminf(ls[2], ls[3])),
                    fminf(fminf(ls[4], ls[5]), fminf(ls[6], ls[7])));
      }
    }
  }
  const int base = (tb + myTok) * 512 + jsl * 32 + slice * 8;
#pragma unroll
  for (int q = 0; q < 8; q++) {
    cand_idx[base + q] = li[q];
    cand_score[base + q] = ls[q];
  }
}

// ---------------------------------------------------------------------------
// K2b: one wave per token. 512 cands -> top-16 by screening score -> exact
// f32 rescore -> exact top-8 (desc score, asc idx) -> softmax -> gather V.
// ---------------------------------------------------------------------------
__global__ __launch_bounds__(256) void k2b_select(
    const float* __restrict__ Qf, const float* __restrict__ Kf,
    const float* __restrict__ V,
    const int* __restrict__ cand_idx, const float* __restrict__ cand_score,
    float* __restrict__ out, float* __restrict__ out_idx,
    float* __restrict__ out_w) {
  const int tid = threadIdx.x;
  const int wv = tid >> 6, lane = tid & 63;
  const int tok = blockIdx.x * 4 + wv;    // 0..8191

  // load 8 candidates per lane (coalesced)
  float sc[8]; int jj[8];
#pragma unroll
  for (int r = 0; r < 8; r++) {
    sc[r] = cand_score[(size_t)tok * 512 + r * 64 + lane];
    jj[r] = cand_idx[(size_t)tok * 512 + r * 64 + lane];
  }

  // top-16 by screening score; round c's winner -> lanes with (lane&15)==c
  int myJ = 0;
#pragma unroll
  for (int c = 0; c < 16; c++) {
    float ms = sc[0]; int mj = jj[0];
#pragma unroll
    for (int r = 1; r < 8; r++) {
      if (sc[r] > ms) { ms = sc[r]; mj = jj[r]; }
    }
#pragma unroll
    for (int d = 1; d < 64; d <<= 1) {
      const float rs = __shfl_xor(ms, d);
      const int rj = __shfl_xor(mj, d);
      if (rs > ms || (rs == ms && rj < mj)) { ms = rs; mj = rj; }
    }
    if ((lane & 15) == c) myJ = mj;
#pragma unroll
    for (int r = 0; r < 8; r++)
      if (jj[r] == mj) sc[r] = -1e30f;
  }

  // exact f32 rescore: 4 lanes per candidate, 16-dim chunks
  const int kc = lane >> 4;
  const float* qp = Qf + (size_t)tok * 64 + kc * 16;
  const float* kp = Kf + (size_t)myJ * 64 + kc * 16;
  float part = 0.f;
#pragma unroll
  for (int e = 0; e < 16; e += 4) {
    const f32x4 qv = *(const f32x4*)(qp + e);
    const f32x4 kv = *(const f32x4*)(kp + e);
    part = fmaf(qv[0], kv[0], part);
    part = fmaf(qv[1], kv[1], part);
    part = fmaf(qv[2], kv[2], part);
    part = fmaf(qv[3], kv[3], part);
  }
  part += __shfl_xor(part, 16);
  part += __shfl_xor(part, 32);
  float cs = part * 0.125f;   // exact score of candidate (lane&15)
  int cj = myJ;

  // exact top-8 over the 16 candidates (4 dup copies are harmless: same j)
  float wsv[8]; int wjv[8];
#pragma unroll
  for (int r = 0; r < 8; r++) {
    float ms = cs; int mj = cj;
#pragma unroll
    for (int d = 1; d < 64; d <<= 1) {
      const float rs = __shfl_xor(ms, d);
      const int rj = __shfl_xor(mj, d);
      if (rs > ms || (rs == ms && rj < mj)) { ms = rs; mj = rj; }
    }
    wsv[r] = ms; wjv[r] = mj;
    if (cj == mj) cs = -1e30f;
  }

  // softmax (redundant on all lanes)
  const float m0 = wsv[0];
  float ex[8], sum = 0.f;
#pragma unroll
  for (int r = 0; r < 8; r++) { ex[r] = expf(wsv[r] - m0); sum += ex[r]; }
  const float inv = 1.f / sum;

  if (lane == 0) {
#pragma unroll
    for (int r = 0; r < 8; r++) {
      out_idx[(size_t)tok * 8 + r] = (float)wjv[r];
      out_w[(size_t)tok * 8 + r] = ex[r] * inv;
    }
  }

  // gather V: lane owns dims [lane*16, +16)
  f32x4 a0 = {0.f,0.f,0.f,0.f}, a1 = a0, a2 = a0, a3 = a0;
#pragma unroll
  for (int r = 0; r < 8; r++) {
    const float w = ex[r] * inv;
    const float* vp = V + (size_t)wjv[r] * 1024 + lane * 16;
    const f32x4 v0 = *(const f32x4*)(vp);
    const f32x4 v1 = *(const f32x4*)(vp + 4);
    const f32x4 v2 = *(const f32x4*)(vp + 8);
    const f32x4 v3 = *(const f32x4*)(vp + 12);
    a0 += w * v0; a1 += w * v1; a2 += w * v2; a3 += w * v3;
  }
  float* op = out + (size_t)tok * 1024 + lane * 16;
  *(f32x4*)(op)      = a0;
  *(f32x4*)(op + 4)  = a1;
  *(f32x4*)(op + 8)  = a2;
  *(f32x4*)(op + 12) = a3;
}

// ---------------------------------------------------------------------------
extern "C" void kernel_launch(void* const* d_in, const int* in_sizes, int n_in,
                              void* d_out, int out_size, void* d_ws, size_t ws_size,
                              hipStream_t stream) {
  const float* x  = (const float*)d_in[0];   // [2,4096,1024]
  const float* mw = (const float*)d_in[1];   // [2,4096,16]
  const float* cn = (const float*)d_in[2];   // [16,1024,64]
  const float* kK = (const float*)d_in[3];   // [16384,64]
  const float* kV = (const float*)d_in[4];   // [16384,1024]

  float* out  = (float*)d_out;               // 8192*1024
  float* oidx = out + (size_t)NTOK * D_MODEL;       // 8192*8
  float* ow   = oidx + (size_t)NTOK * TOPK;         // 8192*8

  // workspace layout. T (33.5 MB) is dead after k1b; candidate arrays reuse it.
  float* T = (float*)d_ws;                                        // 33554432 B
  int*   cand_idx   = (int*)d_ws;                                 // 16777216 B
  float* cand_score = (float*)((char*)d_ws + 16777216);           // 16777216 B
  float* Qf = (float*)((char*)d_ws + 33554432);                   // 2097152 B
  unsigned short* Qb = (unsigned short*)((char*)d_ws + 35651584); // 1048576 B
  unsigned short* Kb = (unsigned short*)((char*)d_ws + 36700160); // 2097152 B

  k1_gemm<<<512, 256, 0, stream>>>(x, cn, T);
  k1b_weight<<<2048, 256, 0, stream>>>(T, mw, Qf, Qb);
  k1c_cvt<<<1024, 256, 0, stream>>>(kK, Kb);
  k2a_screen<<<2048, 256, 0, stream>>>(Qb, Kb, cand_idx, cand_score);
  k2b_select<<<2048, 256, 0, stream>>>(Qf, kK, kV, cand_idx, cand_score,
                                       out, oidx, ow);

  (void)in_sizes; (void)n_in; (void)out_size; (void)ws_size;
}